// Round 9
// baseline (309.905 us; speedup 1.0000x reference)
//
#include <hip/hip_runtime.h>
#include <hip/hip_bf16.h>

typedef unsigned short u16;
typedef __attribute__((ext_vector_type(8))) short bf16x8;
typedef __attribute__((ext_vector_type(4))) float f32x4;
typedef __attribute__((address_space(3))) unsigned lds_u32;
typedef const __attribute__((address_space(1))) unsigned glb_u32;

#define N 256
#define D 128
#define NH 4
#define KD 32
#define NN 65536
#define QK_SCALE 0.17677669529663687f
#define LOG2E 1.4426950408889634f
#define HUGE_MASK 32768.0f

__device__ __forceinline__ float b2f(u16 s) {
  union { float f; unsigned u; } x; x.u = ((unsigned)s) << 16; return x.f;
}
__device__ __forceinline__ u16 f2b(float f) {
  union { float f; unsigned u; } x; x.f = f;
  unsigned r = x.u + 0x7fff + ((x.u >> 16) & 1);
  return (u16)(r >> 16);
}

// ---- Kernel 0: convert 5 weight mats fp32 -> bf16 into the swizzled LDS
// image layout: wb[mat][row*128 + gp*8 + j], gp = (g + (row&15)) & 15.
__global__ __launch_bounds__(256) void prep_w_kernel(
    const float* __restrict__ wq, const float* __restrict__ wk,
    const float* __restrict__ wv, const float* __restrict__ wg,
    const float* __restrict__ wo, u16* __restrict__ wb)
{
  int idx = blockIdx.x * 256 + threadIdx.x;          // 0 .. 10239
  const float* srcs[5] = {wq, wk, wv, wg, wo};
  int mat = idx >> 11, rem = idx & 2047;
  int row = rem >> 4, g = rem & 15;
  int gp = (g + (row & 15)) & 15;
  const float* s = srcs[mat] + row * 128 + g * 8;
  float4 f0 = *(const float4*)(s);
  float4 f1 = *(const float4*)(s + 4);
  uint4 pk;
  pk.x = (unsigned)f2b(f0.x) | ((unsigned)f2b(f0.y) << 16);
  pk.y = (unsigned)f2b(f0.z) | ((unsigned)f2b(f0.w) << 16);
  pk.z = (unsigned)f2b(f1.x) | ((unsigned)f2b(f1.y) << 16);
  pk.w = (unsigned)f2b(f1.z) | ((unsigned)f2b(f1.w) << 16);
  *(uint4*)(wb + (size_t)mat * 16384 + row * 128 + gp * 8) = pk;
}

// Async-stage 32 KB (one swizzled weight mat) global -> LDS, width 16.
__device__ __forceinline__ void async_stage(const u16* __restrict__ gsrc, u16* lds, int tid) {
  int lane = tid & 63, wave = tid >> 6;
  u16* lbase = lds + wave * 512;
  const u16* gbase = gsrc + wave * 512 + lane * 8;
#pragma unroll
  for (int p = 0; p < 8; p++) {
    __builtin_amdgcn_global_load_lds((glb_u32*)(gbase + p * 2048),
                                     (lds_u32*)(lbase + p * 2048), 16, 0, 0);
  }
}

// ---------------- Kernel 1: fused LN + nb + q,k,v,g projections --------------
// q is scaled by QK_SCALE*LOG2E and nb by LOG2E: attention uses exp2 directly.
__global__ __launch_bounds__(256) void projln_kernel(
    const float* __restrict__ pa, const float* __restrict__ lns, const float* __restrict__ lnb,
    const float* __restrict__ w2d, const u16* __restrict__ wb, const float* __restrict__ bg,
    u16* __restrict__ q, u16* __restrict__ k, u16* __restrict__ v, u16* __restrict__ g,
    float* __restrict__ nb)
{
  __shared__ __align__(16) u16 Wl[2][16384];
  int tid = threadIdx.x;
  int wave = tid >> 6, lane = tid & 63;
  int lr = lane & 15, quad = lane >> 4;

  async_stage(wb, Wl[0], tid);   // mat 0 in flight while LN runs

  bf16x8 a[2][4];
#pragma unroll
  for (int mt = 0; mt < 2; mt++) {
    int row = blockIdx.x * 128 + wave * 32 + mt * 16 + lr;
    const float* rp = pa + (size_t)row * D;
    float xv[4][8];
    float s = 0.f, ss = 0.f;
#pragma unroll
    for (int ks = 0; ks < 4; ks++) {
      float4 a0 = *(const float4*)(rp + ks * 32 + quad * 8);
      float4 a1 = *(const float4*)(rp + ks * 32 + quad * 8 + 4);
      xv[ks][0] = a0.x; xv[ks][1] = a0.y; xv[ks][2] = a0.z; xv[ks][3] = a0.w;
      xv[ks][4] = a1.x; xv[ks][5] = a1.y; xv[ks][6] = a1.z; xv[ks][7] = a1.w;
#pragma unroll
      for (int j = 0; j < 8; j++) { s += xv[ks][j]; ss += xv[ks][j] * xv[ks][j]; }
    }
    s  += __shfl_xor(s, 16, 64);  ss += __shfl_xor(ss, 16, 64);
    s  += __shfl_xor(s, 32, 64);  ss += __shfl_xor(ss, 32, 64);
    float mu = s * (1.0f / D);
    float var = ss * (1.0f / D) - mu * mu;
    float rs = rsqrtf(var + 1e-5f);
#pragma unroll
    for (int ks = 0; ks < 4; ks++) {
      float4 s0 = *(const float4*)(lns + ks * 32 + quad * 8);
      float4 s1 = *(const float4*)(lns + ks * 32 + quad * 8 + 4);
      float4 b0 = *(const float4*)(lnb + ks * 32 + quad * 8);
      float4 b1 = *(const float4*)(lnb + ks * 32 + quad * 8 + 4);
      float sc[8] = {s0.x,s0.y,s0.z,s0.w,s1.x,s1.y,s1.z,s1.w};
      float bi[8] = {b0.x,b0.y,b0.z,b0.w,b1.x,b1.y,b1.z,b1.w};
#pragma unroll
      for (int j = 0; j < 8; j++) xv[ks][j] = (xv[ks][j] - mu) * rs * sc[j] + bi[j];
    }
#pragma unroll
    for (int h = 0; h < NH; h++) {
      float p = 0.f;
#pragma unroll
      for (int ks = 0; ks < 4; ks++) {
        float4 w0 = *(const float4*)(w2d + h * D + ks * 32 + quad * 8);
        float4 w1 = *(const float4*)(w2d + h * D + ks * 32 + quad * 8 + 4);
        p += xv[ks][0]*w0.x + xv[ks][1]*w0.y + xv[ks][2]*w0.z + xv[ks][3]*w0.w
           + xv[ks][4]*w1.x + xv[ks][5]*w1.y + xv[ks][6]*w1.z + xv[ks][7]*w1.w;
      }
      p += __shfl_xor(p, 16, 64);
      p += __shfl_xor(p, 32, 64);
      if (quad == 0) nb[(size_t)h * NN + row] = p * LOG2E;
    }
#pragma unroll
    for (int ks = 0; ks < 4; ks++)
#pragma unroll
      for (int j = 0; j < 8; j++) a[mt][ks][j] = (short)f2b(xv[ks][j]);
  }
  __syncthreads();   // drains mat-0 global_load_lds + all waves ready

  u16* Os[4] = {q, k, v, g};
#pragma unroll
  for (int mat = 0; mat < 4; mat++) {
    if (mat < 3) async_stage(wb + (size_t)(mat + 1) * 16384, Wl[(mat + 1) & 1], tid);
    const u16* Wcur = Wl[mat & 1];
    f32x4 acc[2][2][4];
#pragma unroll
    for (int mt = 0; mt < 2; mt++)
#pragma unroll
      for (int tg = 0; tg < 2; tg++)
#pragma unroll
        for (int e = 0; e < 4; e++) acc[mt][tg][e] = (f32x4){0.f, 0.f, 0.f, 0.f};
#pragma unroll
    for (int ks = 0; ks < 4; ks++) {
#pragma unroll
      for (int tg = 0; tg < 2; tg++) {
#pragma unroll
        for (int e = 0; e < 4; e++) {
          int nrow = tg * 64 + 4 * lr + e;
          int gp = (ks * 4 + quad + (nrow & 15)) & 15;
          bf16x8 b = *(const bf16x8*)(&Wcur[nrow * 128 + gp * 8]);
          acc[0][tg][e] = __builtin_amdgcn_mfma_f32_16x16x32_bf16(a[0][ks], b, acc[0][tg][e], 0, 0, 0);
          acc[1][tg][e] = __builtin_amdgcn_mfma_f32_16x16x32_bf16(a[1][ks], b, acc[1][tg][e], 0, 0, 0);
        }
      }
    }
    u16* O = Os[mat];
#pragma unroll
    for (int mt = 0; mt < 2; mt++) {
      int row0 = blockIdx.x * 128 + wave * 32 + mt * 16 + quad * 4;
#pragma unroll
      for (int tg = 0; tg < 2; tg++) {
        int c0 = tg * 64 + 4 * lr;
        float bg0 = 0.f, bg1 = 0.f, bg2 = 0.f, bg3 = 0.f;
        if (mat == 3) { bg0 = bg[c0]; bg1 = bg[c0+1]; bg2 = bg[c0+2]; bg3 = bg[c0+3]; }
#pragma unroll
        for (int reg = 0; reg < 4; reg++) {
          float v0 = acc[mt][tg][0][reg], v1 = acc[mt][tg][1][reg];
          float v2 = acc[mt][tg][2][reg], v3 = acc[mt][tg][3][reg];
          if (mat == 0) {
            v0 *= QK_SCALE * LOG2E; v1 *= QK_SCALE * LOG2E;
            v2 *= QK_SCALE * LOG2E; v3 *= QK_SCALE * LOG2E;
          }
          if (mat == 3) {
            v0 = 1.0f / (1.0f + __expf(-(v0 + bg0)));
            v1 = 1.0f / (1.0f + __expf(-(v1 + bg1)));
            v2 = 1.0f / (1.0f + __expf(-(v2 + bg2)));
            v3 = 1.0f / (1.0f + __expf(-(v3 + bg3)));
          }
          uint2 pk;
          pk.x = (unsigned)f2b(v0) | ((unsigned)f2b(v1) << 16);
          pk.y = (unsigned)f2b(v2) | ((unsigned)f2b(v3) << 16);
          *(uint2*)(O + (size_t)(row0 + reg) * D + c0) = pk;
        }
      }
    }
    __syncthreads();
  }
}

// ---------------- Kernel 2: attention per (r, h) — register-resident P -------
// K rows staged PERMUTED: row j -> tile t = 2*(j>>5) + ((j>>2)&1),
// m-row = 4*((j>>3)&3) + (j&3). Then the QK C-output lane (lr,quad) holds
// S^T[j' = 32*(t>>1) + 8*quad + 4*(t&1) + reg][i0+lr], which after exp/pack is
// EXACTLY the PV B-fragment for ks=t>>1 (j'-bits[4:3] = quad). No P LDS.
__global__ __launch_bounds__(256, 4) void attn_kernel(
    const u16* __restrict__ q, const u16* __restrict__ k, const u16* __restrict__ v,
    const u16* __restrict__ g, const float* __restrict__ nb, const float* __restrict__ mask,
    u16* __restrict__ og)
{
  __shared__ __align__(16) u16 Kf[8192];     // 16 KB (permuted rows)
  __shared__ __align__(16) u16 Vf[8192];     // 16 KB
  __shared__ float bias_lds[256];            // 1 KB  -> 33.8 KB total, 4 blk/CU
  int h = blockIdx.x & 3, r = blockIdx.x >> 2;
  int tid = threadIdx.x;
  {
    int j = tid;
    int tp = 2 * (j >> 5) + ((j >> 2) & 1);
    int mp = 4 * ((j >> 3) & 3) + (j & 3);
    const u16* krow = k + ((size_t)r * N + j) * D + h * KD;
#pragma unroll
    for (int qc = 0; qc < 4; qc++)
      *(bf16x8*)(&Kf[((tp * 4 + qc) * 16 + mp) * 8]) = *(const bf16x8*)(krow + qc * 8);
    const u16* vrow = v + ((size_t)r * N + j) * D + h * KD;
    int ks = j >> 5, qj = (j >> 3) & 3, jj = j & 7;
#pragma unroll
    for (int cc = 0; cc < 32; cc++) {
      int c = (cc + qj * 8) & 31;   // rotate to spread banks across lanes
      Vf[(((ks * 2 + (c & 1)) * 4 + qj) * 16 + (c >> 1)) * 8 + jj] = vrow[c];
    }
    bias_lds[tid] = (HUGE_MASK * LOG2E) * (mask[r * N + tid] - 1.0f);
  }
  __syncthreads();
  int wave = tid >> 6, lane = tid & 63;
  int lr = lane & 15, quad = lane >> 4;

#pragma unroll 1
  for (int pass = 0; pass < 4; pass++) {
    int i0 = pass * 64 + wave * 16;
    size_t base = ((size_t)r * N + i0 + lr) * D + h * KD + quad * 8;
    bf16x8 af = *(const bf16x8*)(q + base);
    bf16x8 gvv = *(const bf16x8*)(g + base);
    f32x4 S[16];
#pragma unroll
    for (int t = 0; t < 16; t++) {
      bf16x8 kf = *(const bf16x8*)(&Kf[((t * 4 + quad) * 16 + lr) * 8]);
      S[t] = __builtin_amdgcn_mfma_f32_16x16x32_bf16(kf, af, (f32x4){0.f,0.f,0.f,0.f}, 0, 0, 0);
    }
    const float* nbrow = nb + (size_t)h * NN + (size_t)(i0 + lr) * N;
    float lsum = 0.f;
    uint2 ps[16];
#pragma unroll
    for (int t = 0; t < 16; t++) {
      int j0 = 32 * (t >> 1) + 8 * quad + 4 * (t & 1);
      float4 nb4 = *(const float4*)(nbrow + j0);
      float4 b4 = *(const float4*)(&bias_lds[j0]);
      float e0 = exp2f(S[t][0] + nb4.x + b4.x);
      float e1 = exp2f(S[t][1] + nb4.y + b4.y);
      float e2 = exp2f(S[t][2] + nb4.z + b4.z);
      float e3 = exp2f(S[t][3] + nb4.w + b4.w);
      lsum += (e0 + e1) + (e2 + e3);
      union { float f; unsigned u; } c0, c1, c2, c3;
      c0.f = e0; c1.f = e1; c2.f = e2; c3.f = e3;
      // bf16 pack via byte-perm: dst = [c0.hi16, c1.hi16]
      ps[t].x = __builtin_amdgcn_perm(c1.u + 0x8000u, c0.u + 0x8000u, 0x07060302u);
      ps[t].y = __builtin_amdgcn_perm(c3.u + 0x8000u, c2.u + 0x8000u, 0x07060302u);
    }
    lsum += __shfl_xor(lsum, 16, 64);
    lsum += __shfl_xor(lsum, 32, 64);
    float inv = __builtin_amdgcn_rcpf(lsum);
    f32x4 o[2] = {(f32x4){0.f,0.f,0.f,0.f}, (f32x4){0.f,0.f,0.f,0.f}};
#pragma unroll
    for (int ks = 0; ks < 8; ks++) {
      union { uint4 u; bf16x8 b; } pb;
      pb.u.x = ps[2 * ks].x;     pb.u.y = ps[2 * ks].y;
      pb.u.z = ps[2 * ks + 1].x; pb.u.w = ps[2 * ks + 1].y;
#pragma unroll
      for (int e = 0; e < 2; e++) {
        bf16x8 vb = *(const bf16x8*)(&Vf[(((ks * 2 + e) * 4 + quad) * 16 + lr) * 8]);
        o[e] = __builtin_amdgcn_mfma_f32_16x16x32_bf16(vb, pb.b, o[e], 0, 0, 0);
      }
    }
    bf16x8 pk8;
#pragma unroll
    for (int reg = 0; reg < 4; reg++) {
#pragma unroll
      for (int e = 0; e < 2; e++) {
        float val = o[e][reg] * inv * b2f((u16)gvv[2 * reg + e]);
        pk8[2 * reg + e] = (short)f2b(val);
      }
    }
    *(bf16x8*)(og + base) = pk8;
  }
}

// ---------------- Kernel 3: output projection (async-staged wo) --------------
__global__ __launch_bounds__(256) void out_kernel(
    const u16* __restrict__ og, const u16* __restrict__ wob, const float* __restrict__ bo,
    const float* __restrict__ mask, float* __restrict__ out)
{
  __shared__ __align__(16) u16 Wlds[16384];
  int tid = threadIdx.x;
  async_stage(wob, Wlds, tid);
  int wave = tid >> 6, lane = tid & 63;
  int lr = lane & 15, quad = lane >> 4;
  bf16x8 a[2][4];
#pragma unroll
  for (int mt = 0; mt < 2; mt++) {
    int arow = blockIdx.x * 128 + wave * 32 + mt * 16 + lr;
#pragma unroll
    for (int ks = 0; ks < 4; ks++)
      a[mt][ks] = *(const bf16x8*)(og + (size_t)arow * D + ks * 32 + quad * 8);
  }
  __syncthreads();
  f32x4 acc[2][2][4];
#pragma unroll
  for (int mt = 0; mt < 2; mt++)
#pragma unroll
    for (int tg = 0; tg < 2; tg++)
#pragma unroll
      for (int e = 0; e < 4; e++) acc[mt][tg][e] = (f32x4){0.f, 0.f, 0.f, 0.f};
#pragma unroll
  for (int ks = 0; ks < 4; ks++) {
#pragma unroll
    for (int tg = 0; tg < 2; tg++) {
#pragma unroll
      for (int e = 0; e < 4; e++) {
        int nrow = tg * 64 + 4 * lr + e;
        int gp = (ks * 4 + quad + (nrow & 15)) & 15;
        bf16x8 b = *(const bf16x8*)(&Wlds[nrow * 128 + gp * 8]);
        acc[0][tg][e] = __builtin_amdgcn_mfma_f32_16x16x32_bf16(a[0][ks], b, acc[0][tg][e], 0, 0, 0);
        acc[1][tg][e] = __builtin_amdgcn_mfma_f32_16x16x32_bf16(a[1][ks], b, acc[1][tg][e], 0, 0, 0);
      }
    }
  }
#pragma unroll
  for (int mt = 0; mt < 2; mt++) {
    int row0 = blockIdx.x * 128 + wave * 32 + mt * 16 + quad * 4;
#pragma unroll
    for (int tg = 0; tg < 2; tg++) {
      int c0 = tg * 64 + 4 * lr;
      float4 bo4 = *(const float4*)(bo + c0);
#pragma unroll
      for (int reg = 0; reg < 4; reg++) {
        int pos = row0 + reg;
        float m = mask[pos];
        float4 o4;
        o4.x = (acc[mt][tg][0][reg] + bo4.x) * m;
        o4.y = (acc[mt][tg][1][reg] + bo4.y) * m;
        o4.z = (acc[mt][tg][2][reg] + bo4.z) * m;
        o4.w = (acc[mt][tg][3][reg] + bo4.w) * m;
        *(float4*)(out + (size_t)pos * D + c0) = o4;
      }
    }
  }
}

extern "C" void kernel_launch(void* const* d_in, const int* in_sizes, int n_in,
                              void* d_out, int out_size, void* d_ws, size_t ws_size,
                              hipStream_t stream)
{
  const float* pa   = (const float*)d_in[0];
  const float* mask = (const float*)d_in[1];
  const float* lns  = (const float*)d_in[2];
  const float* lnb  = (const float*)d_in[3];
  const float* w2d  = (const float*)d_in[4];
  const float* wq   = (const float*)d_in[5];
  const float* wk   = (const float*)d_in[6];
  const float* wv   = (const float*)d_in[7];
  const float* wg   = (const float*)d_in[8];
  const float* bg   = (const float*)d_in[9];
  const float* wo   = (const float*)d_in[10];
  const float* bo   = (const float*)d_in[11];

  const size_t ARR = (size_t)NN * D;     // 8M elements
  u16* q  = (u16*)d_ws;
  u16* k  = q + ARR;
  u16* v  = k + ARR;
  u16* g  = v + ARR;
  u16* og = g + ARR;
  float* nb = (float*)(og + ARR);          // NH*NN floats, natural [h][i][j], x LOG2E
  u16* wb = (u16*)(nb + (size_t)NH * NN);  // 5*16384 u16, swizzled LDS image

  prep_w_kernel<<<40, 256, 0, stream>>>(wq, wk, wv, wg, wo, wb);
  projln_kernel<<<512, 256, 0, stream>>>(pa, lns, lnb, w2d, wb, bg, q, k, v, g, nb);
  attn_kernel<<<N * NH, 256, 0, stream>>>(q, k, v, g, nb, mask, og);
  out_kernel<<<512, 256, 0, stream>>>(og, wb + 4 * 16384, bo, mask, (float*)d_out);
}

// Round 10
// 291.751 us; speedup vs baseline: 1.0622x; 1.0622x over previous
//
#include <hip/hip_runtime.h>
#include <hip/hip_bf16.h>

typedef unsigned short u16;
typedef __attribute__((ext_vector_type(8))) short bf16x8;
typedef __attribute__((ext_vector_type(4))) float f32x4;
typedef __attribute__((address_space(3))) unsigned lds_u32;
typedef const __attribute__((address_space(1))) unsigned glb_u32;

#define N 256
#define D 128
#define NH 4
#define KD 32
#define NN 65536
#define QK_SCALE 0.17677669529663687f
#define LOG2E 1.4426950408889634f
#define HUGE_MASK 32768.0f

__device__ __forceinline__ float b2f(u16 s) {
  union { float f; unsigned u; } x; x.u = ((unsigned)s) << 16; return x.f;
}
__device__ __forceinline__ u16 f2b(float f) {
  union { float f; unsigned u; } x; x.f = f;
  unsigned r = x.u + 0x7fff + ((x.u >> 16) & 1);
  return (u16)(r >> 16);
}

// ---- Kernel 0: convert 5 weight mats fp32 -> bf16 into the swizzled LDS
// image layout: wb[mat][row*128 + gp*8 + j], gp = (g + (row&15)) & 15.
__global__ __launch_bounds__(256) void prep_w_kernel(
    const float* __restrict__ wq, const float* __restrict__ wk,
    const float* __restrict__ wv, const float* __restrict__ wg,
    const float* __restrict__ wo, u16* __restrict__ wb)
{
  int idx = blockIdx.x * 256 + threadIdx.x;          // 0 .. 10239
  const float* srcs[5] = {wq, wk, wv, wg, wo};
  int mat = idx >> 11, rem = idx & 2047;
  int row = rem >> 4, g = rem & 15;
  int gp = (g + (row & 15)) & 15;
  const float* s = srcs[mat] + row * 128 + g * 8;
  float4 f0 = *(const float4*)(s);
  float4 f1 = *(const float4*)(s + 4);
  uint4 pk;
  pk.x = (unsigned)f2b(f0.x) | ((unsigned)f2b(f0.y) << 16);
  pk.y = (unsigned)f2b(f0.z) | ((unsigned)f2b(f0.w) << 16);
  pk.z = (unsigned)f2b(f1.x) | ((unsigned)f2b(f1.y) << 16);
  pk.w = (unsigned)f2b(f1.z) | ((unsigned)f2b(f1.w) << 16);
  *(uint4*)(wb + (size_t)mat * 16384 + row * 128 + gp * 8) = pk;
}

// Async-stage 32 KB (one swizzled weight mat) global -> LDS, width 16.
__device__ __forceinline__ void async_stage(const u16* __restrict__ gsrc, u16* lds, int tid) {
  int lane = tid & 63, wave = tid >> 6;
  u16* lbase = lds + wave * 512;
  const u16* gbase = gsrc + wave * 512 + lane * 8;
#pragma unroll
  for (int p = 0; p < 8; p++) {
    __builtin_amdgcn_global_load_lds((glb_u32*)(gbase + p * 2048),
                                     (lds_u32*)(lbase + p * 2048), 16, 0, 0);
  }
}

// ---------------- Kernel 1: fused LN + nb + q,k,v,g projections --------------
// q is scaled by QK_SCALE*LOG2E and nb by LOG2E: attention uses exp2 directly.
__global__ __launch_bounds__(256) void projln_kernel(
    const float* __restrict__ pa, const float* __restrict__ lns, const float* __restrict__ lnb,
    const float* __restrict__ w2d, const u16* __restrict__ wb, const float* __restrict__ bg,
    u16* __restrict__ q, u16* __restrict__ k, u16* __restrict__ v, u16* __restrict__ g,
    float* __restrict__ nb)
{
  __shared__ __align__(16) u16 Wl[2][16384];
  int tid = threadIdx.x;
  int wave = tid >> 6, lane = tid & 63;
  int lr = lane & 15, quad = lane >> 4;

  async_stage(wb, Wl[0], tid);   // mat 0 in flight while LN runs

  bf16x8 a[2][4];
#pragma unroll
  for (int mt = 0; mt < 2; mt++) {
    int row = blockIdx.x * 128 + wave * 32 + mt * 16 + lr;
    const float* rp = pa + (size_t)row * D;
    float xv[4][8];
    float s = 0.f, ss = 0.f;
#pragma unroll
    for (int ks = 0; ks < 4; ks++) {
      float4 a0 = *(const float4*)(rp + ks * 32 + quad * 8);
      float4 a1 = *(const float4*)(rp + ks * 32 + quad * 8 + 4);
      xv[ks][0] = a0.x; xv[ks][1] = a0.y; xv[ks][2] = a0.z; xv[ks][3] = a0.w;
      xv[ks][4] = a1.x; xv[ks][5] = a1.y; xv[ks][6] = a1.z; xv[ks][7] = a1.w;
#pragma unroll
      for (int j = 0; j < 8; j++) { s += xv[ks][j]; ss += xv[ks][j] * xv[ks][j]; }
    }
    s  += __shfl_xor(s, 16, 64);  ss += __shfl_xor(ss, 16, 64);
    s  += __shfl_xor(s, 32, 64);  ss += __shfl_xor(ss, 32, 64);
    float mu = s * (1.0f / D);
    float var = ss * (1.0f / D) - mu * mu;
    float rs = rsqrtf(var + 1e-5f);
#pragma unroll
    for (int ks = 0; ks < 4; ks++) {
      float4 s0 = *(const float4*)(lns + ks * 32 + quad * 8);
      float4 s1 = *(const float4*)(lns + ks * 32 + quad * 8 + 4);
      float4 b0 = *(const float4*)(lnb + ks * 32 + quad * 8);
      float4 b1 = *(const float4*)(lnb + ks * 32 + quad * 8 + 4);
      float sc[8] = {s0.x,s0.y,s0.z,s0.w,s1.x,s1.y,s1.z,s1.w};
      float bi[8] = {b0.x,b0.y,b0.z,b0.w,b1.x,b1.y,b1.z,b1.w};
#pragma unroll
      for (int j = 0; j < 8; j++) xv[ks][j] = (xv[ks][j] - mu) * rs * sc[j] + bi[j];
    }
#pragma unroll
    for (int h = 0; h < NH; h++) {
      float p = 0.f;
#pragma unroll
      for (int ks = 0; ks < 4; ks++) {
        float4 w0 = *(const float4*)(w2d + h * D + ks * 32 + quad * 8);
        float4 w1 = *(const float4*)(w2d + h * D + ks * 32 + quad * 8 + 4);
        p += xv[ks][0]*w0.x + xv[ks][1]*w0.y + xv[ks][2]*w0.z + xv[ks][3]*w0.w
           + xv[ks][4]*w1.x + xv[ks][5]*w1.y + xv[ks][6]*w1.z + xv[ks][7]*w1.w;
      }
      p += __shfl_xor(p, 16, 64);
      p += __shfl_xor(p, 32, 64);
      if (quad == 0) nb[(size_t)h * NN + row] = p * LOG2E;
    }
#pragma unroll
    for (int ks = 0; ks < 4; ks++)
#pragma unroll
      for (int j = 0; j < 8; j++) a[mt][ks][j] = (short)f2b(xv[ks][j]);
  }
  __syncthreads();   // drains mat-0 global_load_lds + all waves ready

  u16* Os[4] = {q, k, v, g};
#pragma unroll
  for (int mat = 0; mat < 4; mat++) {
    if (mat < 3) async_stage(wb + (size_t)(mat + 1) * 16384, Wl[(mat + 1) & 1], tid);
    const u16* Wcur = Wl[mat & 1];
    f32x4 acc[2][2][4];
#pragma unroll
    for (int mt = 0; mt < 2; mt++)
#pragma unroll
      for (int tg = 0; tg < 2; tg++)
#pragma unroll
        for (int e = 0; e < 4; e++) acc[mt][tg][e] = (f32x4){0.f, 0.f, 0.f, 0.f};
#pragma unroll
    for (int ks = 0; ks < 4; ks++) {
#pragma unroll
      for (int tg = 0; tg < 2; tg++) {
#pragma unroll
        for (int e = 0; e < 4; e++) {
          int nrow = tg * 64 + 4 * lr + e;
          int gp = (ks * 4 + quad + (nrow & 15)) & 15;
          bf16x8 b = *(const bf16x8*)(&Wcur[nrow * 128 + gp * 8]);
          acc[0][tg][e] = __builtin_amdgcn_mfma_f32_16x16x32_bf16(a[0][ks], b, acc[0][tg][e], 0, 0, 0);
          acc[1][tg][e] = __builtin_amdgcn_mfma_f32_16x16x32_bf16(a[1][ks], b, acc[1][tg][e], 0, 0, 0);
        }
      }
    }
    u16* O = Os[mat];
#pragma unroll
    for (int mt = 0; mt < 2; mt++) {
      int row0 = blockIdx.x * 128 + wave * 32 + mt * 16 + quad * 4;
#pragma unroll
      for (int tg = 0; tg < 2; tg++) {
        int c0 = tg * 64 + 4 * lr;
        float bg0 = 0.f, bg1 = 0.f, bg2 = 0.f, bg3 = 0.f;
        if (mat == 3) { bg0 = bg[c0]; bg1 = bg[c0+1]; bg2 = bg[c0+2]; bg3 = bg[c0+3]; }
#pragma unroll
        for (int reg = 0; reg < 4; reg++) {
          float v0 = acc[mt][tg][0][reg], v1 = acc[mt][tg][1][reg];
          float v2 = acc[mt][tg][2][reg], v3 = acc[mt][tg][3][reg];
          if (mat == 0) {
            v0 *= QK_SCALE * LOG2E; v1 *= QK_SCALE * LOG2E;
            v2 *= QK_SCALE * LOG2E; v3 *= QK_SCALE * LOG2E;
          }
          if (mat == 3) {
            v0 = 1.0f / (1.0f + __expf(-(v0 + bg0)));
            v1 = 1.0f / (1.0f + __expf(-(v1 + bg1)));
            v2 = 1.0f / (1.0f + __expf(-(v2 + bg2)));
            v3 = 1.0f / (1.0f + __expf(-(v3 + bg3)));
          }
          uint2 pk;
          pk.x = (unsigned)f2b(v0) | ((unsigned)f2b(v1) << 16);
          pk.y = (unsigned)f2b(v2) | ((unsigned)f2b(v3) << 16);
          *(uint2*)(O + (size_t)(row0 + reg) * D + c0) = pk;
        }
      }
    }
    __syncthreads();
  }
}

// ---------------- Kernel 2: attention per (r, h) — register-resident P -------
// K rows staged PERMUTED (j -> t=2(j>>5)+((j>>2)&1), m=4((j>>3)&3)+(j&3)), so
// QK C-output after exp/pack IS the PV B-fragment. Interleaved at ks
// granularity (2 QK tiles -> exp -> 1 B-frag -> 2 PV MFMAs) to keep register
// liveness low: no spill at __launch_bounds__(256,3).
__global__ __launch_bounds__(256, 3) void attn_kernel(
    const u16* __restrict__ q, const u16* __restrict__ k, const u16* __restrict__ v,
    const u16* __restrict__ g, const float* __restrict__ nb, const float* __restrict__ mask,
    u16* __restrict__ og)
{
  __shared__ __align__(16) u16 Kf[8192];     // 16 KB (permuted rows)
  __shared__ __align__(16) u16 Vf[8192];     // 16 KB
  __shared__ float bias_lds[256];            // 1 KB  -> 33.8 KB total
  int h = blockIdx.x & 3, r = blockIdx.x >> 2;
  int tid = threadIdx.x;
  {
    int j = tid;
    int tp = 2 * (j >> 5) + ((j >> 2) & 1);
    int mp = 4 * ((j >> 3) & 3) + (j & 3);
    const u16* krow = k + ((size_t)r * N + j) * D + h * KD;
#pragma unroll
    for (int qc = 0; qc < 4; qc++)
      *(bf16x8*)(&Kf[((tp * 4 + qc) * 16 + mp) * 8]) = *(const bf16x8*)(krow + qc * 8);
    const u16* vrow = v + ((size_t)r * N + j) * D + h * KD;
    int ks = j >> 5, qj = (j >> 3) & 3, jj = j & 7;
#pragma unroll
    for (int cc = 0; cc < 32; cc++) {
      int c = (cc + qj * 8) & 31;   // rotate to spread banks across lanes
      Vf[(((ks * 2 + (c & 1)) * 4 + qj) * 16 + (c >> 1)) * 8 + jj] = vrow[c];
    }
    bias_lds[tid] = (HUGE_MASK * LOG2E) * (mask[r * N + tid] - 1.0f);
  }
  __syncthreads();
  int wave = tid >> 6, lane = tid & 63;
  int lr = lane & 15, quad = lane >> 4;

  // prefetch q fragments for all passes (hide L2 latency across passes)
  bf16x8 af[4];
#pragma unroll
  for (int pass = 0; pass < 4; pass++) {
    int i0 = pass * 64 + wave * 16;
    af[pass] = *(const bf16x8*)(q + ((size_t)r * N + i0 + lr) * D + h * KD + quad * 8);
  }

#pragma unroll 1
  for (int pass = 0; pass < 4; pass++) {
    int i0 = pass * 64 + wave * 16;
    size_t base = ((size_t)r * N + i0 + lr) * D + h * KD + quad * 8;
    bf16x8 gvv = *(const bf16x8*)(g + base);   // consumed at epilogue only
    const float* nbrow = nb + (size_t)h * NN + (size_t)(i0 + lr) * N + 8 * quad;
    float4 nb0 = *(const float4*)(nbrow);
    float4 nb1 = *(const float4*)(nbrow + 4);
    f32x4 o[2] = {(f32x4){0.f,0.f,0.f,0.f}, (f32x4){0.f,0.f,0.f,0.f}};
    float lsum = 0.f;
#pragma unroll
    for (int ks = 0; ks < 8; ks++) {
      bf16x8 kf0 = *(const bf16x8*)(&Kf[(((2 * ks) * 4 + quad) * 16 + lr) * 8]);
      bf16x8 kf1 = *(const bf16x8*)(&Kf[(((2 * ks + 1) * 4 + quad) * 16 + lr) * 8]);
      f32x4 s0 = __builtin_amdgcn_mfma_f32_16x16x32_bf16(kf0, af[pass], (f32x4){0.f,0.f,0.f,0.f}, 0, 0, 0);
      f32x4 s1 = __builtin_amdgcn_mfma_f32_16x16x32_bf16(kf1, af[pass], (f32x4){0.f,0.f,0.f,0.f}, 0, 0, 0);
      float4 cn0 = nb0, cn1 = nb1;
      if (ks < 7) {   // prefetch next iteration's nb
        nb0 = *(const float4*)(nbrow + 32 * (ks + 1));
        nb1 = *(const float4*)(nbrow + 32 * (ks + 1) + 4);
      }
      float4 bb0 = *(const float4*)(&bias_lds[32 * ks + 8 * quad]);
      float4 bb1 = *(const float4*)(&bias_lds[32 * ks + 8 * quad + 4]);
      float e0 = exp2f(s0[0] + cn0.x + bb0.x);
      float e1 = exp2f(s0[1] + cn0.y + bb0.y);
      float e2 = exp2f(s0[2] + cn0.z + bb0.z);
      float e3 = exp2f(s0[3] + cn0.w + bb0.w);
      float e4 = exp2f(s1[0] + cn1.x + bb1.x);
      float e5 = exp2f(s1[1] + cn1.y + bb1.y);
      float e6 = exp2f(s1[2] + cn1.z + bb1.z);
      float e7 = exp2f(s1[3] + cn1.w + bb1.w);
      lsum += ((e0 + e1) + (e2 + e3)) + ((e4 + e5) + (e6 + e7));
      union { float f; unsigned u; } c0, c1, c2, c3, c4, c5, c6, c7;
      c0.f = e0; c1.f = e1; c2.f = e2; c3.f = e3;
      c4.f = e4; c5.f = e5; c6.f = e6; c7.f = e7;
      union { uint4 u; bf16x8 b; } pb;
      pb.u.x = __builtin_amdgcn_perm(c1.u + 0x8000u, c0.u + 0x8000u, 0x07060302u);
      pb.u.y = __builtin_amdgcn_perm(c3.u + 0x8000u, c2.u + 0x8000u, 0x07060302u);
      pb.u.z = __builtin_amdgcn_perm(c5.u + 0x8000u, c4.u + 0x8000u, 0x07060302u);
      pb.u.w = __builtin_amdgcn_perm(c7.u + 0x8000u, c6.u + 0x8000u, 0x07060302u);
      bf16x8 vb0 = *(const bf16x8*)(&Vf[(((ks * 2 + 0) * 4 + quad) * 16 + lr) * 8]);
      bf16x8 vb1 = *(const bf16x8*)(&Vf[(((ks * 2 + 1) * 4 + quad) * 16 + lr) * 8]);
      o[0] = __builtin_amdgcn_mfma_f32_16x16x32_bf16(vb0, pb.b, o[0], 0, 0, 0);
      o[1] = __builtin_amdgcn_mfma_f32_16x16x32_bf16(vb1, pb.b, o[1], 0, 0, 0);
    }
    lsum += __shfl_xor(lsum, 16, 64);
    lsum += __shfl_xor(lsum, 32, 64);
    float inv = __builtin_amdgcn_rcpf(lsum);
    bf16x8 pk8;
#pragma unroll
    for (int reg = 0; reg < 4; reg++) {
#pragma unroll
      for (int e = 0; e < 2; e++) {
        float val = o[e][reg] * inv * b2f((u16)gvv[2 * reg + e]);
        pk8[2 * reg + e] = (short)f2b(val);
      }
    }
    *(bf16x8*)(og + base) = pk8;
  }
}

// ---------------- Kernel 3: output projection (async-staged wo) --------------
__global__ __launch_bounds__(256) void out_kernel(
    const u16* __restrict__ og, const u16* __restrict__ wob, const float* __restrict__ bo,
    const float* __restrict__ mask, float* __restrict__ out)
{
  __shared__ __align__(16) u16 Wlds[16384];
  int tid = threadIdx.x;
  async_stage(wob, Wlds, tid);
  int wave = tid >> 6, lane = tid & 63;
  int lr = lane & 15, quad = lane >> 4;
  bf16x8 a[2][4];
#pragma unroll
  for (int mt = 0; mt < 2; mt++) {
    int arow = blockIdx.x * 128 + wave * 32 + mt * 16 + lr;
#pragma unroll
    for (int ks = 0; ks < 4; ks++)
      a[mt][ks] = *(const bf16x8*)(og + (size_t)arow * D + ks * 32 + quad * 8);
  }
  __syncthreads();
  f32x4 acc[2][2][4];
#pragma unroll
  for (int mt = 0; mt < 2; mt++)
#pragma unroll
    for (int tg = 0; tg < 2; tg++)
#pragma unroll
      for (int e = 0; e < 4; e++) acc[mt][tg][e] = (f32x4){0.f, 0.f, 0.f, 0.f};
#pragma unroll
  for (int ks = 0; ks < 4; ks++) {
#pragma unroll
    for (int tg = 0; tg < 2; tg++) {
#pragma unroll
      for (int e = 0; e < 4; e++) {
        int nrow = tg * 64 + 4 * lr + e;
        int gp = (ks * 4 + quad + (nrow & 15)) & 15;
        bf16x8 b = *(const bf16x8*)(&Wlds[nrow * 128 + gp * 8]);
        acc[0][tg][e] = __builtin_amdgcn_mfma_f32_16x16x32_bf16(a[0][ks], b, acc[0][tg][e], 0, 0, 0);
        acc[1][tg][e] = __builtin_amdgcn_mfma_f32_16x16x32_bf16(a[1][ks], b, acc[1][tg][e], 0, 0, 0);
      }
    }
  }
#pragma unroll
  for (int mt = 0; mt < 2; mt++) {
    int row0 = blockIdx.x * 128 + wave * 32 + mt * 16 + quad * 4;
#pragma unroll
    for (int tg = 0; tg < 2; tg++) {
      int c0 = tg * 64 + 4 * lr;
      float4 bo4 = *(const float4*)(bo + c0);
#pragma unroll
      for (int reg = 0; reg < 4; reg++) {
        int pos = row0 + reg;
        float m = mask[pos];
        float4 o4;
        o4.x = (acc[mt][tg][0][reg] + bo4.x) * m;
        o4.y = (acc[mt][tg][1][reg] + bo4.y) * m;
        o4.z = (acc[mt][tg][2][reg] + bo4.z) * m;
        o4.w = (acc[mt][tg][3][reg] + bo4.w) * m;
        *(float4*)(out + (size_t)pos * D + c0) = o4;
      }
    }
  }
}

extern "C" void kernel_launch(void* const* d_in, const int* in_sizes, int n_in,
                              void* d_out, int out_size, void* d_ws, size_t ws_size,
                              hipStream_t stream)
{
  const float* pa   = (const float*)d_in[0];
  const float* mask = (const float*)d_in[1];
  const float* lns  = (const float*)d_in[2];
  const float* lnb  = (const float*)d_in[3];
  const float* w2d  = (const float*)d_in[4];
  const float* wq   = (const float*)d_in[5];
  const float* wk   = (const float*)d_in[6];
  const float* wv   = (const float*)d_in[7];
  const float* wg   = (const float*)d_in[8];
  const float* bg   = (const float*)d_in[9];
  const float* wo   = (const float*)d_in[10];
  const float* bo   = (const float*)d_in[11];

  const size_t ARR = (size_t)NN * D;     // 8M elements
  u16* q  = (u16*)d_ws;
  u16* k  = q + ARR;
  u16* v  = k + ARR;
  u16* g  = v + ARR;
  u16* og = g + ARR;
  float* nb = (float*)(og + ARR);          // NH*NN floats, natural [h][i][j], x LOG2E
  u16* wb = (u16*)(nb + (size_t)NH * NN);  // 5*16384 u16, swizzled LDS image

  prep_w_kernel<<<40, 256, 0, stream>>>(wq, wk, wv, wg, wo, wb);
  projln_kernel<<<512, 256, 0, stream>>>(pa, lns, lnb, w2d, wb, bg, q, k, v, g, nb);
  attn_kernel<<<N * NH, 256, 0, stream>>>(q, k, v, g, nb, mask, og);
  out_kernel<<<512, 256, 0, stream>>>(og, wb + 4 * 16384, bo, mask, (float*)d_out);
}

// Round 11
// 193.680 us; speedup vs baseline: 1.6001x; 1.5064x over previous
//
#include <hip/hip_runtime.h>
#include <hip/hip_bf16.h>

typedef unsigned short u16;
typedef __attribute__((ext_vector_type(8))) short bf16x8;
typedef __attribute__((ext_vector_type(4))) float f32x4;
typedef __attribute__((address_space(3))) unsigned lds_u32;
typedef const __attribute__((address_space(1))) unsigned glb_u32;

#define N 256
#define D 128
#define NH 4
#define KD 32
#define NN 65536
#define QK_SCALE 0.17677669529663687f
#define LOG2E 1.4426950408889634f
#define HUGE_MASK 32768.0f

__device__ __forceinline__ float b2f(u16 s) {
  union { float f; unsigned u; } x; x.u = ((unsigned)s) << 16; return x.f;
}
__device__ __forceinline__ u16 f2b(float f) {
  union { float f; unsigned u; } x; x.f = f;
  unsigned r = x.u + 0x7fff + ((x.u >> 16) & 1);
  return (u16)(r >> 16);
}

// ---- Kernel 0: convert 5 weight mats fp32 -> bf16 into the swizzled LDS
// image layout: wb[mat][row*128 + gp*8 + j], gp = (g + (row&15)) & 15.
__global__ __launch_bounds__(256) void prep_w_kernel(
    const float* __restrict__ wq, const float* __restrict__ wk,
    const float* __restrict__ wv, const float* __restrict__ wg,
    const float* __restrict__ wo, u16* __restrict__ wb)
{
  int idx = blockIdx.x * 256 + threadIdx.x;          // 0 .. 10239
  const float* srcs[5] = {wq, wk, wv, wg, wo};
  int mat = idx >> 11, rem = idx & 2047;
  int row = rem >> 4, g = rem & 15;
  int gp = (g + (row & 15)) & 15;
  const float* s = srcs[mat] + row * 128 + g * 8;
  float4 f0 = *(const float4*)(s);
  float4 f1 = *(const float4*)(s + 4);
  uint4 pk;
  pk.x = (unsigned)f2b(f0.x) | ((unsigned)f2b(f0.y) << 16);
  pk.y = (unsigned)f2b(f0.z) | ((unsigned)f2b(f0.w) << 16);
  pk.z = (unsigned)f2b(f1.x) | ((unsigned)f2b(f1.y) << 16);
  pk.w = (unsigned)f2b(f1.z) | ((unsigned)f2b(f1.w) << 16);
  *(uint4*)(wb + (size_t)mat * 16384 + row * 128 + gp * 8) = pk;
}

// Async-stage 32 KB (one swizzled weight mat) global -> LDS, width 16.
__device__ __forceinline__ void async_stage(const u16* __restrict__ gsrc, u16* lds, int tid) {
  int lane = tid & 63, wave = tid >> 6;
  u16* lbase = lds + wave * 512;
  const u16* gbase = gsrc + wave * 512 + lane * 8;
#pragma unroll
  for (int p = 0; p < 8; p++) {
    __builtin_amdgcn_global_load_lds((glb_u32*)(gbase + p * 2048),
                                     (lds_u32*)(lbase + p * 2048), 16, 0, 0);
  }
}

// ---------------- Kernel 1: fused LN + nb + q,k,v,g projections --------------
// q is scaled by QK_SCALE*LOG2E and nb by LOG2E: attention uses exp2 directly.
__global__ __launch_bounds__(256) void projln_kernel(
    const float* __restrict__ pa, const float* __restrict__ lns, const float* __restrict__ lnb,
    const float* __restrict__ w2d, const u16* __restrict__ wb, const float* __restrict__ bg,
    u16* __restrict__ q, u16* __restrict__ k, u16* __restrict__ v, u16* __restrict__ g,
    float* __restrict__ nb)
{
  __shared__ __align__(16) u16 Wl[2][16384];
  int tid = threadIdx.x;
  int wave = tid >> 6, lane = tid & 63;
  int lr = lane & 15, quad = lane >> 4;

  async_stage(wb, Wl[0], tid);   // mat 0 in flight while LN runs

  bf16x8 a[2][4];
#pragma unroll
  for (int mt = 0; mt < 2; mt++) {
    int row = blockIdx.x * 128 + wave * 32 + mt * 16 + lr;
    const float* rp = pa + (size_t)row * D;
    float xv[4][8];
    float s = 0.f, ss = 0.f;
#pragma unroll
    for (int ks = 0; ks < 4; ks++) {
      float4 a0 = *(const float4*)(rp + ks * 32 + quad * 8);
      float4 a1 = *(const float4*)(rp + ks * 32 + quad * 8 + 4);
      xv[ks][0] = a0.x; xv[ks][1] = a0.y; xv[ks][2] = a0.z; xv[ks][3] = a0.w;
      xv[ks][4] = a1.x; xv[ks][5] = a1.y; xv[ks][6] = a1.z; xv[ks][7] = a1.w;
#pragma unroll
      for (int j = 0; j < 8; j++) { s += xv[ks][j]; ss += xv[ks][j] * xv[ks][j]; }
    }
    s  += __shfl_xor(s, 16, 64);  ss += __shfl_xor(ss, 16, 64);
    s  += __shfl_xor(s, 32, 64);  ss += __shfl_xor(ss, 32, 64);
    float mu = s * (1.0f / D);
    float var = ss * (1.0f / D) - mu * mu;
    float rs = rsqrtf(var + 1e-5f);
#pragma unroll
    for (int ks = 0; ks < 4; ks++) {
      float4 s0 = *(const float4*)(lns + ks * 32 + quad * 8);
      float4 s1 = *(const float4*)(lns + ks * 32 + quad * 8 + 4);
      float4 b0 = *(const float4*)(lnb + ks * 32 + quad * 8);
      float4 b1 = *(const float4*)(lnb + ks * 32 + quad * 8 + 4);
      float sc[8] = {s0.x,s0.y,s0.z,s0.w,s1.x,s1.y,s1.z,s1.w};
      float bi[8] = {b0.x,b0.y,b0.z,b0.w,b1.x,b1.y,b1.z,b1.w};
#pragma unroll
      for (int j = 0; j < 8; j++) xv[ks][j] = (xv[ks][j] - mu) * rs * sc[j] + bi[j];
    }
#pragma unroll
    for (int h = 0; h < NH; h++) {
      float p = 0.f;
#pragma unroll
      for (int ks = 0; ks < 4; ks++) {
        float4 w0 = *(const float4*)(w2d + h * D + ks * 32 + quad * 8);
        float4 w1 = *(const float4*)(w2d + h * D + ks * 32 + quad * 8 + 4);
        p += xv[ks][0]*w0.x + xv[ks][1]*w0.y + xv[ks][2]*w0.z + xv[ks][3]*w0.w
           + xv[ks][4]*w1.x + xv[ks][5]*w1.y + xv[ks][6]*w1.z + xv[ks][7]*w1.w;
      }
      p += __shfl_xor(p, 16, 64);
      p += __shfl_xor(p, 32, 64);
      if (quad == 0) nb[(size_t)h * NN + row] = p * LOG2E;
    }
#pragma unroll
    for (int ks = 0; ks < 4; ks++)
#pragma unroll
      for (int j = 0; j < 8; j++) a[mt][ks][j] = (short)f2b(xv[ks][j]);
  }
  __syncthreads();   // drains mat-0 global_load_lds + all waves ready

  u16* Os[4] = {q, k, v, g};
#pragma unroll
  for (int mat = 0; mat < 4; mat++) {
    if (mat < 3) async_stage(wb + (size_t)(mat + 1) * 16384, Wl[(mat + 1) & 1], tid);
    const u16* Wcur = Wl[mat & 1];
    f32x4 acc[2][2][4];
#pragma unroll
    for (int mt = 0; mt < 2; mt++)
#pragma unroll
      for (int tg = 0; tg < 2; tg++)
#pragma unroll
        for (int e = 0; e < 4; e++) acc[mt][tg][e] = (f32x4){0.f, 0.f, 0.f, 0.f};
#pragma unroll
    for (int ks = 0; ks < 4; ks++) {
#pragma unroll
      for (int tg = 0; tg < 2; tg++) {
#pragma unroll
        for (int e = 0; e < 4; e++) {
          int nrow = tg * 64 + 4 * lr + e;
          int gp = (ks * 4 + quad + (nrow & 15)) & 15;
          bf16x8 b = *(const bf16x8*)(&Wcur[nrow * 128 + gp * 8]);
          acc[0][tg][e] = __builtin_amdgcn_mfma_f32_16x16x32_bf16(a[0][ks], b, acc[0][tg][e], 0, 0, 0);
          acc[1][tg][e] = __builtin_amdgcn_mfma_f32_16x16x32_bf16(a[1][ks], b, acc[1][tg][e], 0, 0, 0);
        }
      }
    }
    u16* O = Os[mat];
#pragma unroll
    for (int mt = 0; mt < 2; mt++) {
      int row0 = blockIdx.x * 128 + wave * 32 + mt * 16 + quad * 4;
#pragma unroll
      for (int tg = 0; tg < 2; tg++) {
        int c0 = tg * 64 + 4 * lr;
        float bg0 = 0.f, bg1 = 0.f, bg2 = 0.f, bg3 = 0.f;
        if (mat == 3) { bg0 = bg[c0]; bg1 = bg[c0+1]; bg2 = bg[c0+2]; bg3 = bg[c0+3]; }
#pragma unroll
        for (int reg = 0; reg < 4; reg++) {
          float v0 = acc[mt][tg][0][reg], v1 = acc[mt][tg][1][reg];
          float v2 = acc[mt][tg][2][reg], v3 = acc[mt][tg][3][reg];
          if (mat == 0) {
            v0 *= QK_SCALE * LOG2E; v1 *= QK_SCALE * LOG2E;
            v2 *= QK_SCALE * LOG2E; v3 *= QK_SCALE * LOG2E;
          }
          if (mat == 3) {
            v0 = 1.0f / (1.0f + __expf(-(v0 + bg0)));
            v1 = 1.0f / (1.0f + __expf(-(v1 + bg1)));
            v2 = 1.0f / (1.0f + __expf(-(v2 + bg2)));
            v3 = 1.0f / (1.0f + __expf(-(v3 + bg3)));
          }
          uint2 pk;
          pk.x = (unsigned)f2b(v0) | ((unsigned)f2b(v1) << 16);
          pk.y = (unsigned)f2b(v2) | ((unsigned)f2b(v3) << 16);
          *(uint2*)(O + (size_t)(row0 + reg) * D + c0) = pk;
        }
      }
    }
    __syncthreads();
  }
}

// ---------------- Kernel 2: attention per (r, h) — register-resident P -------
// K rows staged PERMUTED (j -> t=2(j>>5)+((j>>2)&1), m=4((j>>3)&3)+(j&3)), so
// the QK C-output after exp/pack IS the PV B-fragment. Interleaved at ks
// granularity. NO dynamically-indexed local arrays (scratch poison — r10).
__global__ __launch_bounds__(256, 2) void attn_kernel(
    const u16* __restrict__ q, const u16* __restrict__ k, const u16* __restrict__ v,
    const u16* __restrict__ g, const float* __restrict__ nb, const float* __restrict__ mask,
    u16* __restrict__ og)
{
  __shared__ __align__(16) u16 Kf[8192];     // 16 KB (permuted rows)
  __shared__ __align__(16) u16 Vf[8192];     // 16 KB
  __shared__ float bias_lds[256];            // 1 KB  -> 33.8 KB total, 4 blk/CU
  int h = blockIdx.x & 3, r = blockIdx.x >> 2;
  int tid = threadIdx.x;
  {
    int j = tid;
    int tp = 2 * (j >> 5) + ((j >> 2) & 1);
    int mp = 4 * ((j >> 3) & 3) + (j & 3);
    const u16* krow = k + ((size_t)r * N + j) * D + h * KD;
#pragma unroll
    for (int qc = 0; qc < 4; qc++)
      *(bf16x8*)(&Kf[((tp * 4 + qc) * 16 + mp) * 8]) = *(const bf16x8*)(krow + qc * 8);
    const u16* vrow = v + ((size_t)r * N + j) * D + h * KD;
    int ks = j >> 5, qj = (j >> 3) & 3, jj = j & 7;
#pragma unroll
    for (int cc = 0; cc < 32; cc++) {
      int c = (cc + qj * 8) & 31;   // rotate to spread banks across lanes
      Vf[(((ks * 2 + (c & 1)) * 4 + qj) * 16 + (c >> 1)) * 8 + jj] = vrow[c];
    }
    bias_lds[tid] = (HUGE_MASK * LOG2E) * (mask[r * N + tid] - 1.0f);
  }
  __syncthreads();
  int wave = tid >> 6, lane = tid & 63;
  int lr = lane & 15, quad = lane >> 4;

#pragma unroll 1
  for (int pass = 0; pass < 4; pass++) {
    int i0 = pass * 64 + wave * 16;
    size_t base = ((size_t)r * N + i0 + lr) * D + h * KD + quad * 8;
    bf16x8 af = *(const bf16x8*)(q + base);
    const float* nbrow = nb + (size_t)h * NN + (size_t)(i0 + lr) * N + 8 * quad;
    float4 nb0 = *(const float4*)(nbrow);
    float4 nb1 = *(const float4*)(nbrow + 4);
    f32x4 o[2] = {(f32x4){0.f,0.f,0.f,0.f}, (f32x4){0.f,0.f,0.f,0.f}};
    float lsum = 0.f;
#pragma unroll
    for (int ks = 0; ks < 8; ks++) {
      bf16x8 kf0 = *(const bf16x8*)(&Kf[(((2 * ks) * 4 + quad) * 16 + lr) * 8]);
      bf16x8 kf1 = *(const bf16x8*)(&Kf[(((2 * ks + 1) * 4 + quad) * 16 + lr) * 8]);
      f32x4 s0 = __builtin_amdgcn_mfma_f32_16x16x32_bf16(kf0, af, (f32x4){0.f,0.f,0.f,0.f}, 0, 0, 0);
      f32x4 s1 = __builtin_amdgcn_mfma_f32_16x16x32_bf16(kf1, af, (f32x4){0.f,0.f,0.f,0.f}, 0, 0, 0);
      float4 cn0 = nb0, cn1 = nb1;
      if (ks < 7) {   // prefetch next iteration's nb
        nb0 = *(const float4*)(nbrow + 32 * (ks + 1));
        nb1 = *(const float4*)(nbrow + 32 * (ks + 1) + 4);
      }
      float4 bb0 = *(const float4*)(&bias_lds[32 * ks + 8 * quad]);
      float4 bb1 = *(const float4*)(&bias_lds[32 * ks + 8 * quad + 4]);
      float e0 = exp2f(s0[0] + cn0.x + bb0.x);
      float e1 = exp2f(s0[1] + cn0.y + bb0.y);
      float e2 = exp2f(s0[2] + cn0.z + bb0.z);
      float e3 = exp2f(s0[3] + cn0.w + bb0.w);
      float e4 = exp2f(s1[0] + cn1.x + bb1.x);
      float e5 = exp2f(s1[1] + cn1.y + bb1.y);
      float e6 = exp2f(s1[2] + cn1.z + bb1.z);
      float e7 = exp2f(s1[3] + cn1.w + bb1.w);
      lsum += ((e0 + e1) + (e2 + e3)) + ((e4 + e5) + (e6 + e7));
      union { float f; unsigned u; } c0, c1, c2, c3, c4, c5, c6, c7;
      c0.f = e0; c1.f = e1; c2.f = e2; c3.f = e3;
      c4.f = e4; c5.f = e5; c6.f = e6; c7.f = e7;
      union { uint4 u; bf16x8 b; } pb;
      pb.u.x = __builtin_amdgcn_perm(c1.u + 0x8000u, c0.u + 0x8000u, 0x07060302u);
      pb.u.y = __builtin_amdgcn_perm(c3.u + 0x8000u, c2.u + 0x8000u, 0x07060302u);
      pb.u.z = __builtin_amdgcn_perm(c5.u + 0x8000u, c4.u + 0x8000u, 0x07060302u);
      pb.u.w = __builtin_amdgcn_perm(c7.u + 0x8000u, c6.u + 0x8000u, 0x07060302u);
      bf16x8 vb0 = *(const bf16x8*)(&Vf[(((ks * 2 + 0) * 4 + quad) * 16 + lr) * 8]);
      bf16x8 vb1 = *(const bf16x8*)(&Vf[(((ks * 2 + 1) * 4 + quad) * 16 + lr) * 8]);
      o[0] = __builtin_amdgcn_mfma_f32_16x16x32_bf16(vb0, pb.b, o[0], 0, 0, 0);
      o[1] = __builtin_amdgcn_mfma_f32_16x16x32_bf16(vb1, pb.b, o[1], 0, 0, 0);
    }
    lsum += __shfl_xor(lsum, 16, 64);
    lsum += __shfl_xor(lsum, 32, 64);
    float inv = __builtin_amdgcn_rcpf(lsum);
    bf16x8 gvv = *(const bf16x8*)(g + base);   // loaded after ks-loop: no liveness
    bf16x8 pk8;
#pragma unroll
    for (int reg = 0; reg < 4; reg++) {
#pragma unroll
      for (int e = 0; e < 2; e++) {
        float val = o[e][reg] * inv * b2f((u16)gvv[2 * reg + e]);
        pk8[2 * reg + e] = (short)f2b(val);
      }
    }
    *(bf16x8*)(og + base) = pk8;
  }
}

// ---------------- Kernel 3: output projection (async-staged wo) --------------
__global__ __launch_bounds__(256) void out_kernel(
    const u16* __restrict__ og, const u16* __restrict__ wob, const float* __restrict__ bo,
    const float* __restrict__ mask, float* __restrict__ out)
{
  __shared__ __align__(16) u16 Wlds[16384];
  int tid = threadIdx.x;
  async_stage(wob, Wlds, tid);
  int wave = tid >> 6, lane = tid & 63;
  int lr = lane & 15, quad = lane >> 4;
  bf16x8 a[2][4];
#pragma unroll
  for (int mt = 0; mt < 2; mt++) {
    int arow = blockIdx.x * 128 + wave * 32 + mt * 16 + lr;
#pragma unroll
    for (int ks = 0; ks < 4; ks++)
      a[mt][ks] = *(const bf16x8*)(og + (size_t)arow * D + ks * 32 + quad * 8);
  }
  __syncthreads();
  f32x4 acc[2][2][4];
#pragma unroll
  for (int mt = 0; mt < 2; mt++)
#pragma unroll
    for (int tg = 0; tg < 2; tg++)
#pragma unroll
      for (int e = 0; e < 4; e++) acc[mt][tg][e] = (f32x4){0.f, 0.f, 0.f, 0.f};
#pragma unroll
  for (int ks = 0; ks < 4; ks++) {
#pragma unroll
    for (int tg = 0; tg < 2; tg++) {
#pragma unroll
      for (int e = 0; e < 4; e++) {
        int nrow = tg * 64 + 4 * lr + e;
        int gp = (ks * 4 + quad + (nrow & 15)) & 15;
        bf16x8 b = *(const bf16x8*)(&Wlds[nrow * 128 + gp * 8]);
        acc[0][tg][e] = __builtin_amdgcn_mfma_f32_16x16x32_bf16(a[0][ks], b, acc[0][tg][e], 0, 0, 0);
        acc[1][tg][e] = __builtin_amdgcn_mfma_f32_16x16x32_bf16(a[1][ks], b, acc[1][tg][e], 0, 0, 0);
      }
    }
  }
#pragma unroll
  for (int mt = 0; mt < 2; mt++) {
    int row0 = blockIdx.x * 128 + wave * 32 + mt * 16 + quad * 4;
#pragma unroll
    for (int tg = 0; tg < 2; tg++) {
      int c0 = tg * 64 + 4 * lr;
      float4 bo4 = *(const float4*)(bo + c0);
#pragma unroll
      for (int reg = 0; reg < 4; reg++) {
        int pos = row0 + reg;
        float m = mask[pos];
        float4 o4;
        o4.x = (acc[mt][tg][0][reg] + bo4.x) * m;
        o4.y = (acc[mt][tg][1][reg] + bo4.y) * m;
        o4.z = (acc[mt][tg][2][reg] + bo4.z) * m;
        o4.w = (acc[mt][tg][3][reg] + bo4.w) * m;
        *(float4*)(out + (size_t)pos * D + c0) = o4;
      }
    }
  }
}

extern "C" void kernel_launch(void* const* d_in, const int* in_sizes, int n_in,
                              void* d_out, int out_size, void* d_ws, size_t ws_size,
                              hipStream_t stream)
{
  const float* pa   = (const float*)d_in[0];
  const float* mask = (const float*)d_in[1];
  const float* lns  = (const float*)d_in[2];
  const float* lnb  = (const float*)d_in[3];
  const float* w2d  = (const float*)d_in[4];
  const float* wq   = (const float*)d_in[5];
  const float* wk   = (const float*)d_in[6];
  const float* wv   = (const float*)d_in[7];
  const float* wg   = (const float*)d_in[8];
  const float* bg   = (const float*)d_in[9];
  const float* wo   = (const float*)d_in[10];
  const float* bo   = (const float*)d_in[11];

  const size_t ARR = (size_t)NN * D;     // 8M elements
  u16* q  = (u16*)d_ws;
  u16* k  = q + ARR;
  u16* v  = k + ARR;
  u16* g  = v + ARR;
  u16* og = g + ARR;
  float* nb = (float*)(og + ARR);          // NH*NN floats, natural [h][i][j], x LOG2E
  u16* wb = (u16*)(nb + (size_t)NH * NN);  // 5*16384 u16, swizzled LDS image

  prep_w_kernel<<<40, 256, 0, stream>>>(wq, wk, wv, wg, wo, wb);
  projln_kernel<<<512, 256, 0, stream>>>(pa, lns, lnb, w2d, wb, bg, q, k, v, g, nb);
  attn_kernel<<<N * NH, 256, 0, stream>>>(q, k, v, g, nb, mask, og);
  out_kernel<<<512, 256, 0, stream>>>(og, wb + 4 * 16384, bo, mask, (float*)d_out);
}